// Round 3
// baseline (855.731 us; speedup 1.0000x reference)
//
#include <hip/hip_runtime.h>
#include <hip/hip_bf16.h>

#define NFEAT 512
#define NHID  64
#define NCLASS 40

typedef __attribute__((ext_vector_type(8))) __bf16 bf16x8;
typedef __attribute__((ext_vector_type(4))) float  f32x4;

// ---------------- W1 -> W1t (bf16, transposed [NHID][NFEAT]) ----------------
__global__ void k_w1t(const float* __restrict__ W1, __bf16* __restrict__ W1t) {
    int idx = blockIdx.x * 256 + threadIdx.x;
    if (idx >= NFEAT * NHID) return;
    int n = idx & (NHID - 1);
    int k = idx >> 6;
    W1t[(size_t)n * NFEAT + k] = (__bf16)W1[(size_t)k * NHID + n];
}

// ---------------- CSR build ----------------
__global__ void k_hist(const int* __restrict__ row, int* __restrict__ cnt, int E) {
    int i = blockIdx.x * 256 + threadIdx.x;
    if (i < E) atomicAdd(&cnt[row[i]], 1);
}

__global__ void k_scan(const int* __restrict__ cnt, int* __restrict__ rp,
                       int* __restrict__ cur, int n) {
    __shared__ int wsum[16];
    __shared__ int carry_sh;
    const int tid = threadIdx.x;           // 1024 threads
    const int lane = tid & 63, w = tid >> 6;
    if (tid == 0) carry_sh = 0;
    __syncthreads();
    for (int base = 0; base < n; base += 1024) {
        int i = base + tid;
        int v = (i < n) ? cnt[i] : 0;
        int s = v;
        #pragma unroll
        for (int o = 1; o < 64; o <<= 1) { int t = __shfl_up(s, o, 64); if (lane >= o) s += t; }
        if (lane == 63) wsum[w] = s;
        __syncthreads();
        if (w == 0) {
            int xv = (lane < 16) ? wsum[lane] : 0;
            #pragma unroll
            for (int o = 1; o < 16; o <<= 1) { int t = __shfl_up(xv, o, 64); if (lane >= o) xv += t; }
            if (lane < 16) wsum[lane] = xv;
        }
        __syncthreads();
        int carry = carry_sh;
        int excl = carry + (w ? wsum[w - 1] : 0) + s - v;
        if (i < n) { rp[i] = excl; cur[i] = excl; }
        __syncthreads();
        if (tid == 1023) carry_sh = carry + wsum[15];
        __syncthreads();
    }
    if (tid == 0) rp[n] = carry_sh;
}

__global__ void k_scatter(const int* __restrict__ row, const int* __restrict__ col,
                          const float* __restrict__ val, int* __restrict__ cur,
                          int* __restrict__ ccol, float* __restrict__ cval, int E) {
    int i = blockIdx.x * 256 + threadIdx.x;
    if (i >= E) return;
    int r = row[i];
    int p = atomicAdd(&cur[r], 1);
    ccol[p] = col[i];
    cval[p] = val[i];
}

// ---------------- GEMM1: xw = bf16(x) @ bf16(W1), MFMA ----------------
__global__ __launch_bounds__(256) void k_gemm1(const float* __restrict__ x,
        const __bf16* __restrict__ W1t, __bf16* __restrict__ xw, int N) {
    __shared__ __align__(16) __bf16 xs[64][64];
    __shared__ __align__(16) __bf16 ws[64][64];
    const int t = threadIdx.x;
    const int lane = t & 63;
    const int w = t >> 6;
    const int wr = (w >> 1) * 32;     // wave row offset within 64x64 tile
    const int wc = (w & 1) * 32;      // wave col offset
    const int l15 = lane & 15;
    const int l4  = lane >> 4;        // 0..3
    const int row0 = blockIdx.x * 64;

    f32x4 acc[2][2] = {};

    for (int k0 = 0; k0 < NFEAT; k0 += 64) {
        // stage A: x (f32) -> bf16, XOR-swizzled 16B chunks
        #pragma unroll
        for (int s = t; s < 512; s += 256) {
            int r = s >> 3, ch = s & 7;
            int gr = row0 + r;
            float v[8] = {0.f,0.f,0.f,0.f,0.f,0.f,0.f,0.f};
            if (gr < N) {
                const float4* p = (const float4*)(x + (size_t)gr * NFEAT + k0 + ch * 8);
                float4 a0 = p[0], a1 = p[1];
                v[0]=a0.x; v[1]=a0.y; v[2]=a0.z; v[3]=a0.w;
                v[4]=a1.x; v[5]=a1.y; v[6]=a1.z; v[7]=a1.w;
            }
            bf16x8 frag;
            #pragma unroll
            for (int j = 0; j < 8; ++j) frag[j] = (__bf16)v[j];
            *(bf16x8*)&xs[r][((ch ^ (r & 7)) * 8)] = frag;
        }
        // stage B: W1t (bf16 [n][k]) swizzled
        #pragma unroll
        for (int s = t; s < 512; s += 256) {
            int n = s >> 3, ch = s & 7;
            bf16x8 frag = *(const bf16x8*)(W1t + (size_t)n * NFEAT + k0 + ch * 8);
            *(bf16x8*)&ws[n][((ch ^ (n & 7)) * 8)] = frag;
        }
        __syncthreads();
        #pragma unroll
        for (int kh = 0; kh < 2; ++kh) {
            bf16x8 a[2], b[2];
            #pragma unroll
            for (int mi = 0; mi < 2; ++mi) {
                int r = wr + mi * 16 + l15;
                int ch = (kh * 4 + l4) ^ (r & 7);
                a[mi] = *(const bf16x8*)&xs[r][ch * 8];
            }
            #pragma unroll
            for (int ni = 0; ni < 2; ++ni) {
                int n = wc + ni * 16 + l15;
                int ch = (kh * 4 + l4) ^ (n & 7);
                b[ni] = *(const bf16x8*)&ws[n][ch * 8];
            }
            #pragma unroll
            for (int mi = 0; mi < 2; ++mi)
                #pragma unroll
                for (int ni = 0; ni < 2; ++ni)
                    acc[mi][ni] = __builtin_amdgcn_mfma_f32_16x16x32_bf16(a[mi], b[ni], acc[mi][ni], 0, 0, 0);
        }
        __syncthreads();
    }
    // C/D layout: col = lane&15, row = (lane>>4)*4 + reg
    #pragma unroll
    for (int mi = 0; mi < 2; ++mi)
        #pragma unroll
        for (int ni = 0; ni < 2; ++ni)
            #pragma unroll
            for (int j = 0; j < 4; ++j) {
                int r = row0 + wr + mi * 16 + l4 * 4 + j;
                int c = wc + ni * 16 + l15;
                if (r < N) xw[(size_t)r * NHID + c] = (__bf16)acc[mi][ni][j];
            }
}

// ---------------- SPMM1: h1 = relu(adj @ xw + b1) ----------------
__global__ void k_spmm1(const int* __restrict__ rp, const int* __restrict__ ccol,
        const float* __restrict__ cval, const __bf16* __restrict__ xw,
        const float* __restrict__ b1, float* __restrict__ h1, int N) {
    int lane = threadIdx.x & 63;
    int row = blockIdx.x * 4 + (threadIdx.x >> 6);
    if (row >= N) return;
    int e = rp[row], end = rp[row + 1];
    float acc = 0.f;
    for (; e + 1 < end; e += 2) {
        int c0 = ccol[e], c1 = ccol[e + 1];
        float v0 = cval[e], v1 = cval[e + 1];
        float x0 = (float)xw[(size_t)c0 * NHID + lane];
        float x1 = (float)xw[(size_t)c1 * NHID + lane];
        acc += v0 * x0;
        acc += v1 * x1;
    }
    if (e < end) {
        int c0 = ccol[e];
        acc += cval[e] * (float)xw[(size_t)c0 * NHID + lane];
    }
    h1[(size_t)row * NHID + lane] = fmaxf(acc + b1[lane], 0.f);
}

// ---------------- GEMM2: hw = h1 @ W2 ----------------
__global__ __launch_bounds__(128) void k_gemm2(const float* __restrict__ h1,
        const float* __restrict__ W2, float* __restrict__ hw, int N) {
    __shared__ float w2s[NHID * NCLASS];
    for (int i = threadIdx.x; i < NHID * NCLASS; i += 128) w2s[i] = W2[i];
    __syncthreads();
    int row = blockIdx.x * 128 + threadIdx.x;
    if (row >= N) return;
    float acc[NCLASS];
    #pragma unroll
    for (int c = 0; c < NCLASS; ++c) acc[c] = 0.f;
    const float4* hp = (const float4*)(h1 + (size_t)row * NHID);
    #pragma unroll
    for (int k4 = 0; k4 < NHID / 4; ++k4) {
        float4 a = hp[k4];
        const float* wr0 = &w2s[(k4 * 4) * NCLASS];
        #pragma unroll
        for (int c = 0; c < NCLASS; ++c)
            acc[c] += a.x * wr0[c] + a.y * wr0[NCLASS + c]
                    + a.z * wr0[2 * NCLASS + c] + a.w * wr0[3 * NCLASS + c];
    }
    float4* op = (float4*)(hw + (size_t)row * NCLASS);
    #pragma unroll
    for (int c4 = 0; c4 < NCLASS / 4; ++c4)
        op[c4] = make_float4(acc[4*c4], acc[4*c4+1], acc[4*c4+2], acc[4*c4+3]);
}

// ---------------- SPMM2: h2 = adj @ hw + b2 ----------------
__global__ void k_spmm2(const int* __restrict__ rp, const int* __restrict__ ccol,
        const float* __restrict__ cval, const float* __restrict__ hw,
        const float* __restrict__ b2, float* __restrict__ h2, int N) {
    int lane = threadIdx.x & 63;
    int row = blockIdx.x * 4 + (threadIdx.x >> 6);
    if (row >= N) return;
    if (lane >= NCLASS) return;
    int e = rp[row], end = rp[row + 1];
    float acc = 0.f;
    for (; e + 1 < end; e += 2) {
        int c0 = ccol[e], c1 = ccol[e + 1];
        float v0 = cval[e], v1 = cval[e + 1];
        float x0 = hw[(size_t)c0 * NCLASS + lane];
        float x1 = hw[(size_t)c1 * NCLASS + lane];
        acc += v0 * x0;
        acc += v1 * x1;
    }
    if (e < end) acc += cval[e] * hw[(size_t)ccol[e] * NCLASS + lane];
    h2[(size_t)row * NCLASS + lane] = acc + b2[lane];
}

// ---------------- PvT spmm (atomics into zeroed out) ----------------
__global__ void k_pvt(const int* __restrict__ prow, const int* __restrict__ pcol,
        const float* __restrict__ pval, const float* __restrict__ h2,
        float* __restrict__ out, int E2) {
    int gt = blockIdx.x * 256 + threadIdx.x;
    int e = gt >> 6, lane = gt & 63;
    if (e >= E2 || lane >= NCLASS) return;
    int r = prow[e], c = pcol[e];
    float v = pval[e];
    atomicAdd(&out[(size_t)r * NCLASS + lane], v * h2[(size_t)c * NCLASS + lane]);
}

// ---------------- log_softmax in-place ----------------
__global__ void k_lsm(float* __restrict__ out, int N) {
    int lane = threadIdx.x & 63;
    int row = blockIdx.x * 4 + (threadIdx.x >> 6);
    if (row >= N) return;
    float v = (lane < NCLASS) ? out[(size_t)row * NCLASS + lane] : -__builtin_inff();
    float m = v;
    #pragma unroll
    for (int o = 32; o; o >>= 1) m = fmaxf(m, __shfl_xor(m, o, 64));
    float ex = (lane < NCLASS) ? expf(v - m) : 0.f;
    float s = ex;
    #pragma unroll
    for (int o = 32; o; o >>= 1) s += __shfl_xor(s, o, 64);
    if (lane < NCLASS) out[(size_t)row * NCLASS + lane] = v - m - logf(s);
}

extern "C" void kernel_launch(void* const* d_in, const int* in_sizes, int n_in,
                              void* d_out, int out_size, void* d_ws, size_t ws_size,
                              hipStream_t stream) {
    const float* x       = (const float*)d_in[0];
    const int*   adj_row = (const int*)d_in[1];
    const int*   adj_col = (const int*)d_in[2];
    const float* adj_val = (const float*)d_in[3];
    const int*   pvt_row = (const int*)d_in[4];
    const int*   pvt_col = (const int*)d_in[5];
    const float* pvt_val = (const float*)d_in[6];
    const float* W1      = (const float*)d_in[7];
    const float* b1      = (const float*)d_in[8];
    const float* W2      = (const float*)d_in[9];
    const float* b2      = (const float*)d_in[10];
    const int N  = in_sizes[0] / NFEAT;
    const int E  = in_sizes[1];
    const int E2 = in_sizes[4];
    float* out = (float*)d_out;

    char* p = (char*)d_ws;
    auto alloc = [&](size_t bytes) { char* q = p; p += (bytes + 255) & ~(size_t)255; return q; };
    // unionA: xw (bf16, N*64*2=12.8MB) then hw (f32, N*40*4=16MB)
    char* uA = alloc((size_t)N * NCLASS * 4);
    __bf16* xw = (__bf16*)uA;
    float*  hw = (float*)uA;
    // unionB: h1 (f32, N*64*4=25.6MB) then h2 (f32, 16MB)
    char* uB = alloc((size_t)N * NHID * 4);
    float* h1 = (float*)uB;
    float* h2 = (float*)uB;
    int*    cnt  = (int*)alloc((size_t)N * 4);
    int*    rp   = (int*)alloc(((size_t)N + 1) * 4);
    int*    cur  = (int*)alloc((size_t)N * 4);
    int*    ccol = (int*)alloc((size_t)E * 4);
    float*  cval = (float*)alloc((size_t)E * 4);
    __bf16* W1t  = (__bf16*)alloc((size_t)NFEAT * NHID * 2);
    (void)ws_size; (void)n_in; (void)out_size;

    hipMemsetAsync(cnt, 0, (size_t)N * 4, stream);
    k_w1t<<<(NFEAT * NHID + 255) / 256, 256, 0, stream>>>(W1, W1t);
    k_hist<<<(E + 255) / 256, 256, 0, stream>>>(adj_row, cnt, E);
    k_scan<<<1, 1024, 0, stream>>>(cnt, rp, cur, N);
    k_scatter<<<(E + 255) / 256, 256, 0, stream>>>(adj_row, adj_col, adj_val, cur, ccol, cval, E);
    k_gemm1<<<(N + 63) / 64, 256, 0, stream>>>(x, W1t, xw, N);
    k_spmm1<<<(N + 3) / 4, 256, 0, stream>>>(rp, ccol, cval, xw, b1, h1, N);
    k_gemm2<<<(N + 127) / 128, 128, 0, stream>>>(h1, W2, hw, N);
    k_spmm2<<<(N + 3) / 4, 256, 0, stream>>>(rp, ccol, cval, hw, b2, h2, N);
    hipMemsetAsync(out, 0, (size_t)N * NCLASS * 4, stream);
    k_pvt<<<(int)(((size_t)E2 * 64 + 255) / 256), 256, 0, stream>>>(pvt_row, pvt_col, pvt_val, h2, out, E2);
    k_lsm<<<(N + 3) / 4, 256, 0, stream>>>(out, N);
}